// Round 13
// baseline (872.691 us; speedup 1.0000x reference)
//
#include <hip/hip_runtime.h>
#include <math.h>

#define A_N 46035
#define B_N 32
#define M_N 64
#define SEGC 3
#define HW 245760            // 384*640
#define HW4 61440            // HW/4
#define NBP 60               // seg blocks per plane (short blocks backfill det)
#define SEG_BLOCKS (B_N * SEGC * NBP)   // 5760
#define SEG_TOTAL 23592960   // B*SEGC*HW
#define DET_K 2              // anchors per thread (VGPR ~32, 8 waves/SIMD)
#define ABLK 90              // ceil(A_N / (256*DET_K))
#define DET_BLOCKS (ABLK * B_N)         // 2880
#define TOT_BLOCKS (DET_BLOCKS + SEG_BLOCKS)   // 8640
#define F4_PER_BLOCK (HW4 / NBP)        // 1024 -> 4 float4-pairs/thread, 1 batch

// ws layout, all slots written unconditionally each call.
// det partials (double): [3][B_N][ABLK] = 8640 dbl = 69,120 B
// seg partials (float):  [SEGC][4][SEG_S] = 23040 flt = 92,160 B
// done-counter (uint):   4 B at byte offset 161,280 (memset to 0 each call)
// TOTAL = 161,284 B  (proven-safe: < 218,880 B used in R4-R7)
#define DET_WS (3 * B_N * ABLK)   // 8640 doubles
#define SEG_S (B_N * NBP)         // 1920 partials per (c,q)
#define CNT_OFF (DET_WS * 8 + SEGC * 4 * SEG_S * 4)   // 161280

__device__ __forceinline__ double waveRed(double v) {
    for (int o = 32; o; o >>= 1) v += __shfl_down(v, o, 64);
    return v;
}

__device__ __forceinline__ void det_path(
    int blk, const float* __restrict__ cls, const float* __restrict__ reg,
    const float* __restrict__ anc, const float* __restrict__ ann,
    double* __restrict__ ws)
{
    const int b = blk / ABLK;
    const int bx = blk % ABLK;
    const int tid = threadIdx.x;
    const int a_base = bx * (256 * DET_K) + tid;

    __shared__ float4 sbox[M_N];   // x1,y1,x2,y2
    __shared__ float2 sal[M_N];    // area, label
    __shared__ int smv;
    if (tid < M_N) {
        const float* p = &ann[(b * M_N + tid) * 5];
        const float x1 = p[0], y1 = p[1], x2 = p[2], y2 = p[3], lb = p[4];
        sbox[tid] = make_float4(x1, y1, x2, y2);
        sal[tid] = make_float2((x2 - x1) * (y2 - y1), lb);
        // valid boxes are a -1-padded prefix; count them (invalid can never win argmax)
        unsigned long long vm = __ballot(lb != -1.0f);
        if (tid == 0) smv = (int)__popcll(vm);
    }
    __syncthreads();
    const int mv = smv;

    float ax1[DET_K], ay1[DET_K], ax2[DET_K], ay2[DET_K], aarea[DET_K], pc[DET_K];
    float binter[DET_K], bua[DET_K];
    int barg[DET_K];

    #pragma unroll
    for (int k = 0; k < DET_K; ++k) {
        const int a = a_base + k * 256;
        const int al = (a < A_N) ? a : (A_N - 1);
        const float4 av = *reinterpret_cast<const float4*>(&anc[al * 4]);
        ay1[k] = av.x; ax1[k] = av.y; ay2[k] = av.z; ax2[k] = av.w;
        aarea[k] = (av.z - av.x) * (av.w - av.y);
        binter[k] = -1.0f;   // first m always updates: rhs < 0 <= lhs
        bua[k] = 1.0f;
        barg[k] = 0;
        pc[k] = cls[b * A_N + al];   // prefetch, hides under IoU loop
    }

    // key = inter/ab, monotone in IoU = inter/(ab-inter) since inter/ab <= 1/2;
    // cross-multiplied compare (exact, division-free), strict > keeps first-max.
    #pragma unroll 4
    for (int m = 0; m < mv; ++m) {
        const float4 bb = sbox[m];
        const float ba = sal[m].x;
        #pragma unroll
        for (int k = 0; k < DET_K; ++k) {
            const float iw = fmaxf(fminf(ax2[k], bb.z) - fmaxf(ax1[k], bb.x), 0.0f);
            const float ih = fmaxf(fminf(ay2[k], bb.w) - fmaxf(ay1[k], bb.y), 0.0f);
            const float inter = iw * ih;
            const float ab = aarea[k] + ba;   // > 0 always (aarea > 64)
            const bool upd = inter * bua[k] > binter[k] * ab;
            binter[k] = upd ? inter : binter[k];
            bua[k]    = upd ? ab    : bua[k];
            barg[k]   = upd ? m     : barg[k];
        }
    }

    float cls_f = 0.0f, reg_f = 0.0f;
    int pos_i = 0;

    #pragma unroll
    for (int k = 0; k < DET_K; ++k) {
        const int a = a_base + k * 256;
        if (a >= A_N) continue;
        const float4 g = sbox[barg[k]];
        const float2 al2 = sal[barg[k]];

        const bool big = al2.x > 100.0f;
        // IoU >= thr  <=>  binter*(1+thr) >= thr*ab  (ab-form, division-free)
        const float c1 = big ? 1.5f : 1.15f;
        const float thr = big ? 0.5f : 0.15f;
        const bool pos = binter[k] * c1 >= thr * bua[k];
        pos_i += pos ? 1 : 0;

        float p = pc[k];
        p = fminf(fmaxf(p, 1e-4f), 1.0f - 1e-4f);
        const bool t1 = pos && ((int)al2.y == 0);
        const float af = t1 ? 0.25f : 0.75f;
        const float fw = t1 ? (1.0f - p) : p;
        const float bce = t1 ? (-__logf(p)) : (-__logf(1.0f - p));
        cls_f += af * fw * fw * bce;

        if (pos) {
            const float aw = ax2[k] - ax1[k];
            const float ah = ay2[k] - ay1[k];
            const float acx = ax1[k] + 0.5f * aw;
            const float acy = ay1[k] + 0.5f * ah;
            const float gw0 = g.z - g.x;
            const float gh0 = g.w - g.y;
            const float gcx = g.x + 0.5f * gw0;   // centers from UNclamped sizes
            const float gcy = g.y + 0.5f * gh0;
            const float gw = fmaxf(gw0, 1.0f);
            const float gh = fmaxf(gh0, 1.0f);
            const float rah = __builtin_amdgcn_rcpf(ah);
            const float raw = __builtin_amdgcn_rcpf(aw);
            const float t0 = (gcy - acy) * rah;        // tdy
            const float t1r = (gcx - acx) * raw;       // tdx
            const float t2 = __logf(gh * rah);         // tdh
            const float t3 = __logf(gw * raw);         // tdw

            const float4 rv = *reinterpret_cast<const float4*>(&reg[(size_t)(b * A_N + a) * 4]);
            float d, rl, s = 0.0f;
            d = fabsf(t0 - rv.x);  rl = (d <= 1.0f/9.0f) ? 4.5f*d*d : d - 0.5f/9.0f; s += rl;
            d = fabsf(t1r - rv.y); rl = (d <= 1.0f/9.0f) ? 4.5f*d*d : d - 0.5f/9.0f; s += rl;
            d = fabsf(t2 - rv.z);  rl = (d <= 1.0f/9.0f) ? 4.5f*d*d : d - 0.5f/9.0f; s += rl;
            d = fabsf(t3 - rv.w);  rl = (d <= 1.0f/9.0f) ? 4.5f*d*d : d - 0.5f/9.0f; s += rl;
            reg_f += s;
        }
    }

    double cls_c = (double)cls_f, reg_c = (double)reg_f, pos_c = (double)pos_i;

    __shared__ double sredd[3][4];
    const int wid = threadIdx.x >> 6, lane = threadIdx.x & 63;
    cls_c = waveRed(cls_c);
    reg_c = waveRed(reg_c);
    pos_c = waveRed(pos_c);
    if (lane == 0) { sredd[0][wid] = cls_c; sredd[1][wid] = reg_c; sredd[2][wid] = pos_c; }
    __syncthreads();
    if (threadIdx.x == 0) {
        double c = 0, r = 0, pp = 0;
        for (int w = 0; w < 4; ++w) { c += sredd[0][w]; r += sredd[1][w]; pp += sredd[2][w]; }
        ws[0 * (B_N * ABLK) + b * ABLK + bx] = c;
        ws[1 * (B_N * ABLK) + b * ABLK + bx] = r;
        ws[2 * (B_N * ABLK) + b * ABLK + bx] = pp;
    }
}

__device__ __forceinline__ void seg_path(
    int sblk, const float* __restrict__ pred, const float* __restrict__ annot,
    float* __restrict__ seg_ws)
{
    const int plane = sblk / NBP;            // 0..95 (wave-uniform)
    const int bp = sblk % NBP;
    const int c = plane % SEGC;
    const int im = plane / SEGC;
    const long base4 = (long)plane * HW4 + (long)bp * F4_PER_BLOCK;

    const float4* __restrict__ p4 = reinterpret_cast<const float4*>(pred);
    const float4* __restrict__ t4 = reinterpret_cast<const float4*>(annot);

    // one batch: 4 P + 4 T float4 loads, all 8 outstanding together
    float4 P[4], T[4];
    #pragma unroll
    for (int j = 0; j < 4; ++j) {
        const long idx = base4 + (long)(j * 256 + threadIdx.x);
        P[j] = p4[idx];
        T[j] = t4[idx];
    }
    __builtin_amdgcn_sched_barrier(0);   // keep the 8 loads clustered

    float sxy = 0.0f, sx = 0.0f, syv = 0.0f, foc = 0.0f;
    #pragma unroll
    for (int j = 0; j < 4; ++j) {
        const float px[4] = { P[j].x, P[j].y, P[j].z, P[j].w };
        const float tx[4] = { T[j].x, T[j].y, T[j].z, T[j].w };
        #pragma unroll
        for (int e = 0; e < 4; ++e) {
            const float x = px[e], y = tx[e];
            const bool sel = y > 0.5f;
            sxy = fmaf(x, y, sxy);
            sx += x;                       // fp = sum_x - inter, in finalize
            syv += y;
            // focal: s=(2y-1)x; t=e^{-s}; logpt=log(1+t); 1-pt=t/(1+t)
            const float s = sel ? x : -x;
            const float t = __expf(-s);
            const float u = 1.0f + t;
            const float r = __builtin_amdgcn_rcpf(u);
            const float omp = t * r;
            const float logpt = __logf(u);
            const float w = fmaf(y, -0.5f, 0.75f);   // 0.25*y + 0.75*(1-y)
            foc = fmaf(omp * omp * logpt, w, foc);
        }
    }

    double inter = (double)sxy, sxd = (double)sx, ycv = (double)syv, fo = (double)foc;

    __shared__ double sreds[4][4];
    const int wid = threadIdx.x >> 6, lane = threadIdx.x & 63;
    inter = waveRed(inter);
    sxd   = waveRed(sxd);
    ycv   = waveRed(ycv);
    fo    = waveRed(fo);
    if (lane == 0) { sreds[0][wid] = inter; sreds[1][wid] = sxd; sreds[2][wid] = ycv; sreds[3][wid] = fo; }
    __syncthreads();
    if (threadIdx.x == 0) {
        double a = 0, b2 = 0, cc = 0, dd = 0;
        for (int w = 0; w < 4; ++w) { a += sreds[0][w]; b2 += sreds[1][w]; cc += sreds[2][w]; dd += sreds[3][w]; }
        const int s = im * NBP + bp;         // 0..1919
        // float partial stores (block partials of <=16K-element sums; final
        // accumulation is done in double in finalize)
        seg_ws[(c * 4 + 0) * SEG_S + s] = (float)a;
        seg_ws[(c * 4 + 1) * SEG_S + s] = (float)b2;
        seg_ws[(c * 4 + 2) * SEG_S + s] = (float)cc;
        seg_ws[(c * 4 + 3) * SEG_S + s] = (float)dd;
    }
}

__device__ void finalize(const double* __restrict__ ws, float* __restrict__ out)
{
    __shared__ double sseg[SEGC][4];   // [c][q]
    __shared__ double sdet[3][B_N];    // [q][b]

    const int t = threadIdx.x;
    const int wv = t >> 6, lane = t & 63;
    const float* seg_ws = reinterpret_cast<const float*>(ws + DET_WS);

    if (wv < 3) {
        // waves 0..2: each handles 4 of the 12 (c,q) seg reductions (1920 floats each)
        for (int pi = 0; pi < 4; ++pi) {
            const int pair = wv * 4 + pi;
            const int c = pair >> 2, q = pair & 3;
            const float* base = seg_ws + (c * 4 + q) * SEG_S;
            double s = 0.0;
            #pragma unroll
            for (int i = 0; i < SEG_S / 64; ++i)    // 30
                s += (double)base[i * 64 + lane];
            s = waveRed(s);
            if (lane == 0) sseg[c][q] = s;
        }
    } else {
        // wave 3: 96 det (q,b) reductions over 64 lanes (ABLK=90 values each)
        for (int task = lane; task < 96; task += 64) {
            const int q = task / 32, b = task % 32;
            const double* base = ws + q * (B_N * ABLK) + b * ABLK;
            double s = 0.0;
            for (int i = 0; i < ABLK; ++i) s += base[i];
            sdet[q][b] = s;
        }
    }
    __syncthreads();

    if (t == 0) {
        double clsm = 0.0, regm = 0.0;
        for (int b = 0; b < B_N; ++b) {
            const double np_ = sdet[2][b];
            const double mnp = fmax(np_, 1.0);
            clsm += sdet[0][b] / mnp;
            regm += (np_ > 0.0) ? sdet[1][b] / (4.0 * mnp) : 0.0;
        }
        clsm /= (double)B_N;
        regm = regm / (double)B_N * 50.0;

        double tsum = 0.0;
        for (int c = 0; c < SEGC; ++c) {
            const double inter = sseg[c][0];
            const double fpv = sseg[c][1] - inter;     // sum_x - inter
            const double ycnt = sseg[c][2];
            const double fnv = ycnt - inter;
            const double denom = fmax(inter + 0.7 * fpv + 0.3 * fnv, 1e-7);
            const double score = inter / denom;
            const double mask = (ycnt > 0.0) ? 1.0 : 0.0;
            tsum += (1.0 - score) * mask;
        }
        const double tv = pow(tsum / 3.0, 4.0 / 3.0);
        double focm = 0.0;
        for (int c = 0; c < SEGC; ++c) focm += sseg[c][3];
        focm /= (double)SEG_TOTAL;

        out[0] = (float)clsm;
        out[1] = (float)regm;
        out[2] = (float)(tv + focm);
    }
}

__global__ __launch_bounds__(256) void fused_kernel(
    const float* __restrict__ cls, const float* __restrict__ reg,
    const float* __restrict__ anc, const float* __restrict__ ann,
    const float* __restrict__ pred, const float* __restrict__ annot,
    double* __restrict__ ws, float* __restrict__ out)
{
    const int blk = blockIdx.x;
    // det blocks FIRST: long det blocks all start early; short seg blocks
    // backfill behind them -> no low-occupancy det tail (R6 vs R7-R11 lesson)
    if (blk < DET_BLOCKS) {
        det_path(blk, cls, reg, anc, ann, ws);
    } else {
        seg_path(blk - DET_BLOCKS, pred, annot,
                 reinterpret_cast<float*>(ws + DET_WS));
    }

    // last-block finalize (rocPRIM/CUB pattern): counter zeroed by the host-side
    // hipMemsetAsync each call; partial slots all overwritten each call.
    unsigned* cnt = reinterpret_cast<unsigned*>(
        reinterpret_cast<char*>(ws) + CNT_OFF);
    __shared__ unsigned sLast;
    __threadfence();   // make this block's partial stores device-visible
    if (threadIdx.x == 0)
        sLast = (atomicAdd(cnt, 1u) == (unsigned)(TOT_BLOCKS - 1));
    __syncthreads();
    if (sLast) {
        __threadfence();   // acquire: see all other blocks' partials
        finalize(ws, out);
    }
}

extern "C" void kernel_launch(void* const* d_in, const int* in_sizes, int n_in,
                              void* d_out, int out_size, void* d_ws, size_t ws_size,
                              hipStream_t stream) {
    const float* cls    = (const float*)d_in[0];  // [B,A,1]
    const float* reg    = (const float*)d_in[1];  // [B,A,4]
    const float* anc    = (const float*)d_in[2];  // [1,A,4]
    const float* ann    = (const float*)d_in[3];  // [B,M,5]
    const float* seg    = (const float*)d_in[4];  // [B,3,H,W]
    const float* segann = (const float*)d_in[5];  // [B,3,H,W]
    double* ws = (double*)d_ws;
    float* out = (float*)d_out;

    hipMemsetAsync((char*)d_ws + CNT_OFF, 0, 4, stream);   // zero done-counter

    fused_kernel<<<TOT_BLOCKS, 256, 0, stream>>>(
        cls, reg, anc, ann, seg, segann, ws, out);
}

// Round 14
// 68.332 us; speedup vs baseline: 12.7714x; 12.7714x over previous
//
#include <hip/hip_runtime.h>
#include <math.h>

#define A_N 46035
#define B_N 32
#define M_N 64
#define SEGC 3
#define HW 245760            // 384*640
#define HW4 61440            // HW/4
#define NBP 60               // seg blocks per plane (short blocks backfill det)
#define SEG_BLOCKS (B_N * SEGC * NBP)   // 5760
#define SEG_TOTAL 23592960   // B*SEGC*HW
#define DET_K 2              // anchors per thread (VGPR ~32, 8 waves/SIMD)
#define ABLK 90              // ceil(A_N / (256*DET_K))
#define DET_BLOCKS (ABLK * B_N)         // 2880
#define F4_PER_BLOCK (HW4 / NBP)        // 1024 -> 4 float4-pairs/thread, 1 batch

// ws layout, all slots written unconditionally each call.
// det partials (double): [3][B_N][ABLK] = 8640 dbl = 69,120 B
// seg partials (float):  [SEGC][4][SEG_S] = 23040 flt = 92,160 B
// TOTAL = 161,280 B — R12-proven-safe footprint.
#define DET_WS (3 * B_N * ABLK)   // 8640 doubles
#define SEG_S (B_N * NBP)         // 1920 partials per (c,q)

__device__ __forceinline__ double waveRed(double v) {
    for (int o = 32; o; o >>= 1) v += __shfl_down(v, o, 64);
    return v;
}

__device__ __forceinline__ void det_path(
    int blk, const float* __restrict__ cls, const float* __restrict__ reg,
    const float* __restrict__ anc, const float* __restrict__ ann,
    double* __restrict__ ws)
{
    const int b = blk / ABLK;
    const int bx = blk % ABLK;
    const int tid = threadIdx.x;
    const int a_base = bx * (256 * DET_K) + tid;

    __shared__ float4 sbox[M_N];    // x1,y1,x2,y2
    __shared__ float sarea[M_N];    // box area (inner loop: single-float broadcast)
    __shared__ float slabel[M_N];   // label (epilogue only)
    __shared__ int smv;
    if (tid < M_N) {
        const float* p = &ann[(b * M_N + tid) * 5];
        const float x1 = p[0], y1 = p[1], x2 = p[2], y2 = p[3], lb = p[4];
        sbox[tid] = make_float4(x1, y1, x2, y2);
        sarea[tid] = (x2 - x1) * (y2 - y1);
        slabel[tid] = lb;
        // valid boxes are a -1-padded prefix; count them (invalid can never win argmax)
        unsigned long long vm = __ballot(lb != -1.0f);
        if (tid == 0) smv = (int)__popcll(vm);
    }
    __syncthreads();
    const int mv = smv;

    float ax1[DET_K], ay1[DET_K], ax2[DET_K], ay2[DET_K], aarea[DET_K], pc[DET_K];
    float best[DET_K];
    int barg[DET_K];

    #pragma unroll
    for (int k = 0; k < DET_K; ++k) {
        const int a = a_base + k * 256;
        const int al = (a < A_N) ? a : (A_N - 1);
        const float4 av = *reinterpret_cast<const float4*>(&anc[al * 4]);
        ay1[k] = av.x; ax1[k] = av.y; ay2[k] = av.z; ax2[k] = av.w;
        aarea[k] = (av.z - av.x) * (av.w - av.y);
        best[k] = -1.0f;   // v >= 0 at m=0 -> always updates -> barg=0 default
        barg[k] = 0;
        pc[k] = cls[b * A_N + al];   // prefetch, hides under IoU loop
    }

    // key = inter/ab (monotone in IoU = inter/(ab-inter) since inter/ab <= 1/2).
    // rcp-key: 1-ulp approx only affects exact-tie argmax picks; epilogue
    // recomputes the selected box's inter/ab EXACTLY (R11-validated pattern).
    #pragma unroll 4
    for (int m = 0; m < mv; ++m) {
        const float4 bb = sbox[m];
        const float ba = sarea[m];
        #pragma unroll
        for (int k = 0; k < DET_K; ++k) {
            const float iw = fmaxf(fminf(ax2[k], bb.z) - fmaxf(ax1[k], bb.x), 0.0f);
            const float ih = fmaxf(fminf(ay2[k], bb.w) - fmaxf(ay1[k], bb.y), 0.0f);
            const float inter = iw * ih;
            const float ab = aarea[k] + ba;   // > 0 always (aarea > 64)
            const float v = inter * __builtin_amdgcn_rcpf(ab);  // TRANS pipe
            const bool upd = v > best[k];
            best[k] = upd ? v : best[k];
            barg[k] = upd ? m : barg[k];
        }
    }

    float cls_f = 0.0f, reg_f = 0.0f;
    int pos_i = 0;

    #pragma unroll
    for (int k = 0; k < DET_K; ++k) {
        const int a = a_base + k * 256;
        if (a >= A_N) continue;
        const float4 g = sbox[barg[k]];
        const float garea = sarea[barg[k]];
        const float glabel = slabel[barg[k]];

        // EXACT recompute of the selected box's overlap (removes rcp-key
        // approximation from thresholds and targets)
        const float iw = fmaxf(fminf(ax2[k], g.z) - fmaxf(ax1[k], g.x), 0.0f);
        const float ih = fmaxf(fminf(ay2[k], g.w) - fmaxf(ay1[k], g.y), 0.0f);
        const float binter = iw * ih;
        const float bab = aarea[k] + garea;

        const bool big = garea > 100.0f;
        // IoU >= thr  <=>  binter*(1+thr) >= thr*bab  (division-free, exact)
        const float c1 = big ? 1.5f : 1.15f;
        const float thr = big ? 0.5f : 0.15f;
        const bool pos = binter * c1 >= thr * bab;
        pos_i += pos ? 1 : 0;

        float p = pc[k];
        p = fminf(fmaxf(p, 1e-4f), 1.0f - 1e-4f);
        const bool t1 = pos && ((int)glabel == 0);
        const float af = t1 ? 0.25f : 0.75f;
        const float fw = t1 ? (1.0f - p) : p;
        const float bce = t1 ? (-__logf(p)) : (-__logf(1.0f - p));
        cls_f += af * fw * fw * bce;

        if (pos) {
            const float aw = ax2[k] - ax1[k];
            const float ah = ay2[k] - ay1[k];
            const float acx = ax1[k] + 0.5f * aw;
            const float acy = ay1[k] + 0.5f * ah;
            const float gw0 = g.z - g.x;
            const float gh0 = g.w - g.y;
            const float gcx = g.x + 0.5f * gw0;   // centers from UNclamped sizes
            const float gcy = g.y + 0.5f * gh0;
            const float gw = fmaxf(gw0, 1.0f);
            const float gh = fmaxf(gh0, 1.0f);
            const float rah = __builtin_amdgcn_rcpf(ah);
            const float raw = __builtin_amdgcn_rcpf(aw);
            const float t0 = (gcy - acy) * rah;        // tdy
            const float t1r = (gcx - acx) * raw;       // tdx
            const float t2 = __logf(gh * rah);         // tdh
            const float t3 = __logf(gw * raw);         // tdw

            const float4 rv = *reinterpret_cast<const float4*>(&reg[(size_t)(b * A_N + a) * 4]);
            float d, rl, s = 0.0f;
            d = fabsf(t0 - rv.x);  rl = (d <= 1.0f/9.0f) ? 4.5f*d*d : d - 0.5f/9.0f; s += rl;
            d = fabsf(t1r - rv.y); rl = (d <= 1.0f/9.0f) ? 4.5f*d*d : d - 0.5f/9.0f; s += rl;
            d = fabsf(t2 - rv.z);  rl = (d <= 1.0f/9.0f) ? 4.5f*d*d : d - 0.5f/9.0f; s += rl;
            d = fabsf(t3 - rv.w);  rl = (d <= 1.0f/9.0f) ? 4.5f*d*d : d - 0.5f/9.0f; s += rl;
            reg_f += s;
        }
    }

    double cls_c = (double)cls_f, reg_c = (double)reg_f, pos_c = (double)pos_i;

    __shared__ double sredd[3][4];
    const int wid = threadIdx.x >> 6, lane = threadIdx.x & 63;
    cls_c = waveRed(cls_c);
    reg_c = waveRed(reg_c);
    pos_c = waveRed(pos_c);
    if (lane == 0) { sredd[0][wid] = cls_c; sredd[1][wid] = reg_c; sredd[2][wid] = pos_c; }
    __syncthreads();
    if (threadIdx.x == 0) {
        double c = 0, r = 0, pp = 0;
        for (int w = 0; w < 4; ++w) { c += sredd[0][w]; r += sredd[1][w]; pp += sredd[2][w]; }
        ws[0 * (B_N * ABLK) + b * ABLK + bx] = c;
        ws[1 * (B_N * ABLK) + b * ABLK + bx] = r;
        ws[2 * (B_N * ABLK) + b * ABLK + bx] = pp;
    }
}

__device__ __forceinline__ void seg_path(
    int sblk, const float* __restrict__ pred, const float* __restrict__ annot,
    float* __restrict__ seg_ws)
{
    const int plane = sblk / NBP;            // 0..95 (wave-uniform)
    const int bp = sblk % NBP;
    const int c = plane % SEGC;
    const int im = plane / SEGC;
    const long base4 = (long)plane * HW4 + (long)bp * F4_PER_BLOCK;

    const float4* __restrict__ p4 = reinterpret_cast<const float4*>(pred);
    const float4* __restrict__ t4 = reinterpret_cast<const float4*>(annot);

    // one batch: 4 P + 4 T float4 loads, all 8 outstanding together
    float4 P[4], T[4];
    #pragma unroll
    for (int j = 0; j < 4; ++j) {
        const long idx = base4 + (long)(j * 256 + threadIdx.x);
        P[j] = p4[idx];
        T[j] = t4[idx];
    }
    __builtin_amdgcn_sched_barrier(0);   // keep the 8 loads clustered

    float sxy = 0.0f, sx = 0.0f, syv = 0.0f, foc = 0.0f;
    #pragma unroll
    for (int j = 0; j < 4; ++j) {
        const float px[4] = { P[j].x, P[j].y, P[j].z, P[j].w };
        const float tx[4] = { T[j].x, T[j].y, T[j].z, T[j].w };
        #pragma unroll
        for (int e = 0; e < 4; ++e) {
            const float x = px[e], y = tx[e];
            const bool sel = y > 0.5f;
            sxy = fmaf(x, y, sxy);
            sx += x;                       // fp = sum_x - inter, in finalize
            syv += y;
            // focal: s=(2y-1)x; t=e^{-s}; logpt=log(1+t); 1-pt=t/(1+t)
            const float s = sel ? x : -x;
            const float t = __expf(-s);
            const float u = 1.0f + t;
            const float r = __builtin_amdgcn_rcpf(u);
            const float omp = t * r;
            const float logpt = __logf(u);
            const float w = fmaf(y, -0.5f, 0.75f);   // 0.25*y + 0.75*(1-y)
            foc = fmaf(omp * omp * logpt, w, foc);
        }
    }

    double inter = (double)sxy, sxd = (double)sx, ycv = (double)syv, fo = (double)foc;

    __shared__ double sreds[4][4];
    const int wid = threadIdx.x >> 6, lane = threadIdx.x & 63;
    inter = waveRed(inter);
    sxd   = waveRed(sxd);
    ycv   = waveRed(ycv);
    fo    = waveRed(fo);
    if (lane == 0) { sreds[0][wid] = inter; sreds[1][wid] = sxd; sreds[2][wid] = ycv; sreds[3][wid] = fo; }
    __syncthreads();
    if (threadIdx.x == 0) {
        double a = 0, b2 = 0, cc = 0, dd = 0;
        for (int w = 0; w < 4; ++w) { a += sreds[0][w]; b2 += sreds[1][w]; cc += sreds[2][w]; dd += sreds[3][w]; }
        const int s = im * NBP + bp;         // 0..1919
        // float partial stores (block partials of <=16K-element sums; final
        // accumulation is done in double in fin_kernel)
        seg_ws[(c * 4 + 0) * SEG_S + s] = (float)a;
        seg_ws[(c * 4 + 1) * SEG_S + s] = (float)b2;
        seg_ws[(c * 4 + 2) * SEG_S + s] = (float)cc;
        seg_ws[(c * 4 + 3) * SEG_S + s] = (float)dd;
    }
}

__global__ __launch_bounds__(256) void fused_kernel(
    const float* __restrict__ cls, const float* __restrict__ reg,
    const float* __restrict__ anc, const float* __restrict__ ann,
    const float* __restrict__ pred, const float* __restrict__ annot,
    double* __restrict__ ws)
{
    const int blk = blockIdx.x;
    // det blocks FIRST: long det blocks all start early; short seg blocks
    // backfill behind them -> no low-occupancy det tail (R6 vs R7-R11 lesson)
    if (blk < DET_BLOCKS) {
        det_path(blk, cls, reg, anc, ann, ws);
    } else {
        seg_path(blk - DET_BLOCKS, pred, annot,
                 reinterpret_cast<float*>(ws + DET_WS));
    }
}

__global__ __launch_bounds__(1024) void fin_kernel(
    const double* __restrict__ ws, float* __restrict__ out)
{
    __shared__ double sseg[SEGC][4];   // [c][q]
    __shared__ double sdet[3][B_N];    // [q][b]

    const int t = threadIdx.x;
    const float* seg_ws = reinterpret_cast<const float*>(ws + DET_WS);

    // threads 0..767: 12 waves, one per (c,q) seg reduce over 1920 float partials
    if (t < 768) {
        const int w = t >> 6, lane = t & 63;
        const int c = w >> 2, q = w & 3;
        const float* base = seg_ws + (c * 4 + q) * SEG_S;
        double s = 0.0;
        #pragma unroll
        for (int i = 0; i < SEG_S / 64; ++i)
            s += (double)base[i * 64 + lane];
        s = waveRed(s);
        if (lane == 0) sseg[c][q] = s;
    } else if (t < 768 + 96) {
        // threads 768..863: det reduce, one thread per (q,b), ABLK values each
        const int r = t - 768;
        const int q = r >> 5, b = r & 31;
        const double* base = ws + q * (B_N * ABLK) + b * ABLK;
        double s = 0.0;
        for (int i = 0; i < ABLK; ++i) s += base[i];
        sdet[q][b] = s;
    }
    __syncthreads();

    if (t == 0) {
        double clsm = 0.0, regm = 0.0;
        for (int b = 0; b < B_N; ++b) {
            const double np_ = sdet[2][b];
            const double mnp = fmax(np_, 1.0);
            clsm += sdet[0][b] / mnp;
            regm += (np_ > 0.0) ? sdet[1][b] / (4.0 * mnp) : 0.0;
        }
        clsm /= (double)B_N;
        regm = regm / (double)B_N * 50.0;

        double tsum = 0.0;
        for (int c = 0; c < SEGC; ++c) {
            const double inter = sseg[c][0];
            const double fpv = sseg[c][1] - inter;     // sum_x - inter
            const double ycnt = sseg[c][2];
            const double fnv = ycnt - inter;
            const double denom = fmax(inter + 0.7 * fpv + 0.3 * fnv, 1e-7);
            const double score = inter / denom;
            const double mask = (ycnt > 0.0) ? 1.0 : 0.0;
            tsum += (1.0 - score) * mask;
        }
        const double tv = pow(tsum / 3.0, 4.0 / 3.0);
        double focm = 0.0;
        for (int c = 0; c < SEGC; ++c) focm += sseg[c][3];
        focm /= (double)SEG_TOTAL;

        out[0] = (float)clsm;
        out[1] = (float)regm;
        out[2] = (float)(tv + focm);
    }
}

extern "C" void kernel_launch(void* const* d_in, const int* in_sizes, int n_in,
                              void* d_out, int out_size, void* d_ws, size_t ws_size,
                              hipStream_t stream) {
    const float* cls    = (const float*)d_in[0];  // [B,A,1]
    const float* reg    = (const float*)d_in[1];  // [B,A,4]
    const float* anc    = (const float*)d_in[2];  // [1,A,4]
    const float* ann    = (const float*)d_in[3];  // [B,M,5]
    const float* seg    = (const float*)d_in[4];  // [B,3,H,W]
    const float* segann = (const float*)d_in[5];  // [B,3,H,W]
    double* ws = (double*)d_ws;
    float* out = (float*)d_out;

    fused_kernel<<<DET_BLOCKS + SEG_BLOCKS, 256, 0, stream>>>(
        cls, reg, anc, ann, seg, segann, ws);
    fin_kernel<<<1, 1024, 0, stream>>>(ws, out);
}

// Round 15
// 63.686 us; speedup vs baseline: 13.7030x; 1.0729x over previous
//
#include <hip/hip_runtime.h>
#include <math.h>

#define A_N 46035
#define B_N 32
#define M_N 64
#define SEGC 3
#define HW 245760            // 384*640
#define HW4 61440            // HW/4
#define NBP 60               // seg blocks per plane (short blocks backfill det)
#define SEG_BLOCKS (B_N * SEGC * NBP)   // 5760
#define SEG_TOTAL 23592960   // B*SEGC*HW
#define DET_K 2              // anchors per thread (VGPR ~32, 8 waves/SIMD)
#define ABLK 90              // ceil(A_N / (256*DET_K))
#define DET_BLOCKS (ABLK * B_N)         // 2880
#define F4_PER_BLOCK (HW4 / NBP)        // 1024 -> 4 float4-pairs/thread, 1 batch

// ws layout, all slots written unconditionally each call.
// det partials (double): [3][B_N][ABLK] = 8640 dbl = 69,120 B
// seg partials (float):  [SEGC][4][SEG_S] = 23040 flt = 92,160 B
// TOTAL = 161,280 B — R12-proven-safe footprint.
#define DET_WS (3 * B_N * ABLK)   // 8640 doubles
#define SEG_S (B_N * NBP)         // 1920 partials per (c,q)

__device__ __forceinline__ double waveRed(double v) {
    for (int o = 32; o; o >>= 1) v += __shfl_down(v, o, 64);
    return v;
}

__device__ __forceinline__ void det_path(
    int blk, const float* __restrict__ cls, const float* __restrict__ reg,
    const float* __restrict__ anc, const float* __restrict__ ann,
    double* __restrict__ ws)
{
    const int b = blk / ABLK;
    const int bx = blk % ABLK;
    const int tid = threadIdx.x;
    const int a_base = bx * (256 * DET_K) + tid;

    __shared__ float4 sbox[M_N];   // x1,y1,x2,y2
    __shared__ float2 sal[M_N];    // area, label
    __shared__ int smv;
    if (tid < M_N) {
        const float* p = &ann[(b * M_N + tid) * 5];
        const float x1 = p[0], y1 = p[1], x2 = p[2], y2 = p[3], lb = p[4];
        sbox[tid] = make_float4(x1, y1, x2, y2);
        sal[tid] = make_float2((x2 - x1) * (y2 - y1), lb);
        // valid boxes are a -1-padded prefix; count them (invalid can never win argmax)
        unsigned long long vm = __ballot(lb != -1.0f);
        if (tid == 0) smv = (int)__popcll(vm);
    }
    __syncthreads();
    const int mv = smv;

    float ax1[DET_K], ay1[DET_K], ax2[DET_K], ay2[DET_K], aarea[DET_K], pc[DET_K];
    float binter[DET_K], bua[DET_K];
    int barg[DET_K];

    #pragma unroll
    for (int k = 0; k < DET_K; ++k) {
        const int a = a_base + k * 256;
        const int al = (a < A_N) ? a : (A_N - 1);
        const float4 av = *reinterpret_cast<const float4*>(&anc[al * 4]);
        ay1[k] = av.x; ax1[k] = av.y; ay2[k] = av.z; ax2[k] = av.w;
        aarea[k] = (av.z - av.x) * (av.w - av.y);
        binter[k] = -1.0f;   // first m always updates: rhs < 0 <= lhs
        bua[k] = 1.0f;
        barg[k] = 0;
        pc[k] = cls[b * A_N + al];   // prefetch, hides under IoU loop
    }

    // key = inter/ab, monotone in IoU = inter/(ab-inter) since inter/ab <= 1/2;
    // cross-multiplied compare (exact, division-free), strict > keeps first-max.
    #pragma unroll 4
    for (int m = 0; m < mv; ++m) {
        const float4 bb = sbox[m];
        const float ba = sal[m].x;
        #pragma unroll
        for (int k = 0; k < DET_K; ++k) {
            const float iw = fmaxf(fminf(ax2[k], bb.z) - fmaxf(ax1[k], bb.x), 0.0f);
            const float ih = fmaxf(fminf(ay2[k], bb.w) - fmaxf(ay1[k], bb.y), 0.0f);
            const float inter = iw * ih;
            const float ab = aarea[k] + ba;   // > 0 always (aarea > 64)
            const bool upd = inter * bua[k] > binter[k] * ab;
            binter[k] = upd ? inter : binter[k];
            bua[k]    = upd ? ab    : bua[k];
            barg[k]   = upd ? m     : barg[k];
        }
    }

    float cls_f = 0.0f, reg_f = 0.0f;
    int pos_i = 0;

    #pragma unroll
    for (int k = 0; k < DET_K; ++k) {
        const int a = a_base + k * 256;
        if (a >= A_N) continue;
        const float4 g = sbox[barg[k]];
        const float2 al2 = sal[barg[k]];

        const bool big = al2.x > 100.0f;
        // IoU >= thr  <=>  binter*(1+thr) >= thr*ab  (ab-form, division-free)
        const float c1 = big ? 1.5f : 1.15f;
        const float thr = big ? 0.5f : 0.15f;
        const bool pos = binter[k] * c1 >= thr * bua[k];
        pos_i += pos ? 1 : 0;

        float p = pc[k];
        p = fminf(fmaxf(p, 1e-4f), 1.0f - 1e-4f);
        const bool t1 = pos && ((int)al2.y == 0);
        const float af = t1 ? 0.25f : 0.75f;
        const float fw = t1 ? (1.0f - p) : p;
        const float bce = t1 ? (-__logf(p)) : (-__logf(1.0f - p));
        cls_f += af * fw * fw * bce;

        if (pos) {
            const float aw = ax2[k] - ax1[k];
            const float ah = ay2[k] - ay1[k];
            const float acx = ax1[k] + 0.5f * aw;
            const float acy = ay1[k] + 0.5f * ah;
            const float gw0 = g.z - g.x;
            const float gh0 = g.w - g.y;
            const float gcx = g.x + 0.5f * gw0;   // centers from UNclamped sizes
            const float gcy = g.y + 0.5f * gh0;
            const float gw = fmaxf(gw0, 1.0f);
            const float gh = fmaxf(gh0, 1.0f);
            const float rah = __builtin_amdgcn_rcpf(ah);
            const float raw = __builtin_amdgcn_rcpf(aw);
            const float t0 = (gcy - acy) * rah;        // tdy
            const float t1r = (gcx - acx) * raw;       // tdx
            const float t2 = __logf(gh * rah);         // tdh
            const float t3 = __logf(gw * raw);         // tdw

            const float4 rv = *reinterpret_cast<const float4*>(&reg[(size_t)(b * A_N + a) * 4]);
            float d, rl, s = 0.0f;
            d = fabsf(t0 - rv.x);  rl = (d <= 1.0f/9.0f) ? 4.5f*d*d : d - 0.5f/9.0f; s += rl;
            d = fabsf(t1r - rv.y); rl = (d <= 1.0f/9.0f) ? 4.5f*d*d : d - 0.5f/9.0f; s += rl;
            d = fabsf(t2 - rv.z);  rl = (d <= 1.0f/9.0f) ? 4.5f*d*d : d - 0.5f/9.0f; s += rl;
            d = fabsf(t3 - rv.w);  rl = (d <= 1.0f/9.0f) ? 4.5f*d*d : d - 0.5f/9.0f; s += rl;
            reg_f += s;
        }
    }

    double cls_c = (double)cls_f, reg_c = (double)reg_f, pos_c = (double)pos_i;

    __shared__ double sredd[3][4];
    const int wid = threadIdx.x >> 6, lane = threadIdx.x & 63;
    cls_c = waveRed(cls_c);
    reg_c = waveRed(reg_c);
    pos_c = waveRed(pos_c);
    if (lane == 0) { sredd[0][wid] = cls_c; sredd[1][wid] = reg_c; sredd[2][wid] = pos_c; }
    __syncthreads();
    if (threadIdx.x == 0) {
        double c = 0, r = 0, pp = 0;
        for (int w = 0; w < 4; ++w) { c += sredd[0][w]; r += sredd[1][w]; pp += sredd[2][w]; }
        ws[0 * (B_N * ABLK) + b * ABLK + bx] = c;
        ws[1 * (B_N * ABLK) + b * ABLK + bx] = r;
        ws[2 * (B_N * ABLK) + b * ABLK + bx] = pp;
    }
}

__device__ __forceinline__ void seg_path(
    int sblk, const float* __restrict__ pred, const float* __restrict__ annot,
    float* __restrict__ seg_ws)
{
    const int plane = sblk / NBP;            // 0..95 (wave-uniform)
    const int bp = sblk % NBP;
    const int c = plane % SEGC;
    const int im = plane / SEGC;
    const long base4 = (long)plane * HW4 + (long)bp * F4_PER_BLOCK;

    const float4* __restrict__ p4 = reinterpret_cast<const float4*>(pred);
    const float4* __restrict__ t4 = reinterpret_cast<const float4*>(annot);

    // one batch: 4 P + 4 T float4 loads, all 8 outstanding together
    float4 P[4], T[4];
    #pragma unroll
    for (int j = 0; j < 4; ++j) {
        const long idx = base4 + (long)(j * 256 + threadIdx.x);
        P[j] = p4[idx];
        T[j] = t4[idx];
    }
    __builtin_amdgcn_sched_barrier(0);   // keep the 8 loads clustered

    float sxy = 0.0f, sx = 0.0f, syv = 0.0f, foc = 0.0f;
    #pragma unroll
    for (int j = 0; j < 4; ++j) {
        const float px[4] = { P[j].x, P[j].y, P[j].z, P[j].w };
        const float tx[4] = { T[j].x, T[j].y, T[j].z, T[j].w };
        #pragma unroll
        for (int e = 0; e < 4; ++e) {
            const float x = px[e], y = tx[e];
            const bool sel = y > 0.5f;
            sxy = fmaf(x, y, sxy);
            sx += x;                       // fp = sum_x - inter, in finalize
            syv += y;
            // focal: s=(2y-1)x; t=e^{-s}; logpt=log(1+t); 1-pt=t/(1+t)
            const float s = sel ? x : -x;
            const float t = __expf(-s);
            const float u = 1.0f + t;
            const float r = __builtin_amdgcn_rcpf(u);
            const float omp = t * r;
            const float logpt = __logf(u);
            const float w = fmaf(y, -0.5f, 0.75f);   // 0.25*y + 0.75*(1-y)
            foc = fmaf(omp * omp * logpt, w, foc);
        }
    }

    double inter = (double)sxy, sxd = (double)sx, ycv = (double)syv, fo = (double)foc;

    __shared__ double sreds[4][4];
    const int wid = threadIdx.x >> 6, lane = threadIdx.x & 63;
    inter = waveRed(inter);
    sxd   = waveRed(sxd);
    ycv   = waveRed(ycv);
    fo    = waveRed(fo);
    if (lane == 0) { sreds[0][wid] = inter; sreds[1][wid] = sxd; sreds[2][wid] = ycv; sreds[3][wid] = fo; }
    __syncthreads();
    if (threadIdx.x == 0) {
        double a = 0, b2 = 0, cc = 0, dd = 0;
        for (int w = 0; w < 4; ++w) { a += sreds[0][w]; b2 += sreds[1][w]; cc += sreds[2][w]; dd += sreds[3][w]; }
        const int s = im * NBP + bp;         // 0..1919
        // float partial stores (block partials of <=16K-element sums; final
        // accumulation is done in double in fin_kernel)
        seg_ws[(c * 4 + 0) * SEG_S + s] = (float)a;
        seg_ws[(c * 4 + 1) * SEG_S + s] = (float)b2;
        seg_ws[(c * 4 + 2) * SEG_S + s] = (float)cc;
        seg_ws[(c * 4 + 3) * SEG_S + s] = (float)dd;
    }
}

__global__ __launch_bounds__(256) void fused_kernel(
    const float* __restrict__ cls, const float* __restrict__ reg,
    const float* __restrict__ anc, const float* __restrict__ ann,
    const float* __restrict__ pred, const float* __restrict__ annot,
    double* __restrict__ ws)
{
    const int blk = blockIdx.x;
    // det blocks FIRST: long det blocks all start early; short seg blocks
    // backfill behind them -> no low-occupancy det tail (R6 vs R7-R11 lesson)
    if (blk < DET_BLOCKS) {
        det_path(blk, cls, reg, anc, ann, ws);
    } else {
        seg_path(blk - DET_BLOCKS, pred, annot,
                 reinterpret_cast<float*>(ws + DET_WS));
    }
}

__global__ __launch_bounds__(1024) void fin_kernel(
    const double* __restrict__ ws, float* __restrict__ out)
{
    __shared__ double sseg[SEGC][4];   // [c][q]
    __shared__ double sdet[3][B_N];    // [q][b]

    const int t = threadIdx.x;
    const float* seg_ws = reinterpret_cast<const float*>(ws + DET_WS);

    // threads 0..767: 12 waves, one per (c,q) seg reduce over 1920 float partials
    if (t < 768) {
        const int w = t >> 6, lane = t & 63;
        const int c = w >> 2, q = w & 3;
        const float* base = seg_ws + (c * 4 + q) * SEG_S;
        double s = 0.0;
        #pragma unroll
        for (int i = 0; i < SEG_S / 64; ++i)
            s += (double)base[i * 64 + lane];
        s = waveRed(s);
        if (lane == 0) sseg[c][q] = s;
    } else if (t < 768 + 96) {
        // threads 768..863: det reduce, one thread per (q,b), ABLK values each
        const int r = t - 768;
        const int q = r >> 5, b = r & 31;
        const double* base = ws + q * (B_N * ABLK) + b * ABLK;
        double s = 0.0;
        for (int i = 0; i < ABLK; ++i) s += base[i];
        sdet[q][b] = s;
    }
    __syncthreads();

    if (t == 0) {
        double clsm = 0.0, regm = 0.0;
        for (int b = 0; b < B_N; ++b) {
            const double np_ = sdet[2][b];
            const double mnp = fmax(np_, 1.0);
            clsm += sdet[0][b] / mnp;
            regm += (np_ > 0.0) ? sdet[1][b] / (4.0 * mnp) : 0.0;
        }
        clsm /= (double)B_N;
        regm = regm / (double)B_N * 50.0;

        double tsum = 0.0;
        for (int c = 0; c < SEGC; ++c) {
            const double inter = sseg[c][0];
            const double fpv = sseg[c][1] - inter;     // sum_x - inter
            const double ycnt = sseg[c][2];
            const double fnv = ycnt - inter;
            const double denom = fmax(inter + 0.7 * fpv + 0.3 * fnv, 1e-7);
            const double score = inter / denom;
            const double mask = (ycnt > 0.0) ? 1.0 : 0.0;
            tsum += (1.0 - score) * mask;
        }
        const double tv = pow(tsum / 3.0, 4.0 / 3.0);
        double focm = 0.0;
        for (int c = 0; c < SEGC; ++c) focm += sseg[c][3];
        focm /= (double)SEG_TOTAL;

        out[0] = (float)clsm;
        out[1] = (float)regm;
        out[2] = (float)(tv + focm);
    }
}

extern "C" void kernel_launch(void* const* d_in, const int* in_sizes, int n_in,
                              void* d_out, int out_size, void* d_ws, size_t ws_size,
                              hipStream_t stream) {
    const float* cls    = (const float*)d_in[0];  // [B,A,1]
    const float* reg    = (const float*)d_in[1];  // [B,A,4]
    const float* anc    = (const float*)d_in[2];  // [1,A,4]
    const float* ann    = (const float*)d_in[3];  // [B,M,5]
    const float* seg    = (const float*)d_in[4];  // [B,3,H,W]
    const float* segann = (const float*)d_in[5];  // [B,3,H,W]
    double* ws = (double*)d_ws;
    float* out = (float*)d_out;

    fused_kernel<<<DET_BLOCKS + SEG_BLOCKS, 256, 0, stream>>>(
        cls, reg, anc, ann, seg, segann, ws);
    fin_kernel<<<1, 1024, 0, stream>>>(ws, out);
}